// Round 1
// baseline (224.570 us; speedup 1.0000x reference)
//
#include <hip/hip_runtime.h>
#include <hip/hip_bf16.h>

#define DIN 136
#define HH  128
#define ROWS 128      // rows per block in scores kernel
#define NTHREADS 256
#define NSEQ 256      // N
#define NB   256      // B

// ---------------------------------------------------------------------------
// Kernel 1: scores = MLP(features).  One block = 128 rows (b,n) flattened.
// Thread layout: t = rg*32 + hq;  rg in [0,8) owns rows rg*16..rg*16+15,
// hq in [0,32) owns output columns hq*4..hq*4+3.
// ---------------------------------------------------------------------------
__global__ __launch_bounds__(NTHREADS)
void scores_kernel(const float* __restrict__ features,
                   const float* __restrict__ W1, const float* __restrict__ b1,
                   const float* __restrict__ W2, const float* __restrict__ b2,
                   const float* __restrict__ W3, const float* __restrict__ b3,
                   float* __restrict__ scores)
{
    __shared__ float fbuf[ROWS][DIN];   // 69632 B
    __shared__ float hbuf[ROWS][HH];    // 65536 B  (total 132 KiB LDS)

    const int t   = threadIdx.x;
    const int hq  = t & 31;   // column quad
    const int rg  = t >> 5;   // row group (16 rows each)
    const long row0 = (long)blockIdx.x * ROWS;

    // ---- stage features tile (contiguous 128*136 floats) ----
    const float* fsrc = features + row0 * DIN;
    for (int i = t; i < ROWS * DIN; i += NTHREADS)
        ((float*)fbuf)[i] = fsrc[i];
    __syncthreads();

    float acc[16][4];

    // ---- layer 1: h1 = relu(f @ W1 + b1) ----
    {
        const float4 bv = *(const float4*)&b1[hq * 4];
#pragma unroll
        for (int rr = 0; rr < 16; ++rr) {
            acc[rr][0] = bv.x; acc[rr][1] = bv.y;
            acc[rr][2] = bv.z; acc[rr][3] = bv.w;
        }
        for (int d4 = 0; d4 < DIN / 4; ++d4) {
            const float4 w0 = *(const float4*)&W1[(d4 * 4 + 0) * HH + hq * 4];
            const float4 w1 = *(const float4*)&W1[(d4 * 4 + 1) * HH + hq * 4];
            const float4 w2 = *(const float4*)&W1[(d4 * 4 + 2) * HH + hq * 4];
            const float4 w3 = *(const float4*)&W1[(d4 * 4 + 3) * HH + hq * 4];
#pragma unroll
            for (int rr = 0; rr < 16; ++rr) {
                const float4 f = *(const float4*)&fbuf[rg * 16 + rr][d4 * 4];
                acc[rr][0] += f.x * w0.x + f.y * w1.x + f.z * w2.x + f.w * w3.x;
                acc[rr][1] += f.x * w0.y + f.y * w1.y + f.z * w2.y + f.w * w3.y;
                acc[rr][2] += f.x * w0.z + f.y * w1.z + f.z * w2.z + f.w * w3.z;
                acc[rr][3] += f.x * w0.w + f.y * w1.w + f.z * w2.w + f.w * w3.w;
            }
        }
#pragma unroll
        for (int rr = 0; rr < 16; ++rr) {
            float4 v;
            v.x = fmaxf(acc[rr][0], 0.f); v.y = fmaxf(acc[rr][1], 0.f);
            v.z = fmaxf(acc[rr][2], 0.f); v.w = fmaxf(acc[rr][3], 0.f);
            *(float4*)&hbuf[rg * 16 + rr][hq * 4] = v;
        }
        __syncthreads();
    }

    // ---- layer 2: h2 = relu(h1 @ W2 + b2) ----
    {
        const float4 bv = *(const float4*)&b2[hq * 4];
        float acc2[16][4];
#pragma unroll
        for (int rr = 0; rr < 16; ++rr) {
            acc2[rr][0] = bv.x; acc2[rr][1] = bv.y;
            acc2[rr][2] = bv.z; acc2[rr][3] = bv.w;
        }
        for (int d4 = 0; d4 < HH / 4; ++d4) {
            const float4 w0 = *(const float4*)&W2[(d4 * 4 + 0) * HH + hq * 4];
            const float4 w1 = *(const float4*)&W2[(d4 * 4 + 1) * HH + hq * 4];
            const float4 w2 = *(const float4*)&W2[(d4 * 4 + 2) * HH + hq * 4];
            const float4 w3 = *(const float4*)&W2[(d4 * 4 + 3) * HH + hq * 4];
#pragma unroll
            for (int rr = 0; rr < 16; ++rr) {
                const float4 f = *(const float4*)&hbuf[rg * 16 + rr][d4 * 4];
                acc2[rr][0] += f.x * w0.x + f.y * w1.x + f.z * w2.x + f.w * w3.x;
                acc2[rr][1] += f.x * w0.y + f.y * w1.y + f.z * w2.y + f.w * w3.y;
                acc2[rr][2] += f.x * w0.z + f.y * w1.z + f.z * w2.z + f.w * w3.z;
                acc2[rr][3] += f.x * w0.w + f.y * w1.w + f.z * w2.w + f.w * w3.w;
            }
        }
#pragma unroll
        for (int rr = 0; rr < 16; ++rr) {
            acc[rr][0] = fmaxf(acc2[rr][0], 0.f);
            acc[rr][1] = fmaxf(acc2[rr][1], 0.f);
            acc[rr][2] = fmaxf(acc2[rr][2], 0.f);
            acc[rr][3] = fmaxf(acc2[rr][3], 0.f);
        }
    }

    // ---- layer 3: score = h2 @ W3 + b3, reduce across the 32 hq lanes ----
    {
        const float4 w = *(const float4*)&W3[hq * 4];
        const float bias = b3[0];
#pragma unroll
        for (int rr = 0; rr < 16; ++rr) {
            float p = acc[rr][0] * w.x + acc[rr][1] * w.y +
                      acc[rr][2] * w.z + acc[rr][3] * w.w;
            // hq spans lanes 0..31 within each 32-lane half of the wave64
            p += __shfl_xor(p, 16, 64);
            p += __shfl_xor(p, 8, 64);
            p += __shfl_xor(p, 4, 64);
            p += __shfl_xor(p, 2, 64);
            p += __shfl_xor(p, 1, 64);
            if (hq == 0)
                scores[row0 + rg * 16 + rr] = p + bias;
        }
    }
}

// ---------------------------------------------------------------------------
// Kernel 2: pairwise LambdaRank reduction. One block per query b; thread i
// owns row i; loops over j using dndcg symmetry + sig(-d) = 1 - sig(d).
// ---------------------------------------------------------------------------
__global__ __launch_bounds__(NSEQ)
void lambda_kernel(const float* __restrict__ scores,
                   const int* __restrict__ labels,
                   float* __restrict__ out)
{
    __shared__ float s_sc[NSEQ];
    __shared__ float s_gain[NSEQ];
    __shared__ int   s_lab[NSEQ];

    const int b = blockIdx.x;
    const int i = threadIdx.x;
    const float si = scores[b * NSEQ + i];
    const int   li = labels[b * NSEQ + i];
    s_sc[i]   = si;
    s_lab[i]  = li;
    s_gain[i] = exp2f((float)li);
    __syncthreads();

    const float gi = s_gain[i];
    float accum = 0.f;
    for (int j = 0; j < NSEQ; ++j) {
        const int lj = s_lab[j];
        if (li == lj) continue;                 // includes j == i
        const float sj = s_sc[j];
        const float mx = fmaxf(si, sj);
        const float dn = fabsf((gi - s_gain[j]) / (1.f + log2f(1.f + mx)));
        const float sig = 1.f / (1.f + expf(-(si - sj)));   // sigmoid(si-sj)
        // li>lj:  +0.5*sig*dn   (A[i][j] term)
        // lj>li:  -0.5*(1-sig)*dn  (A[j][i] term, sig(sj-si)=1-sig)
        accum += (li > lj) ? 0.5f * sig * dn : -0.5f * (1.f - sig) * dn;
    }
    out[b * NSEQ + i] = accum;
}

// ---------------------------------------------------------------------------
extern "C" void kernel_launch(void* const* d_in, const int* in_sizes, int n_in,
                              void* d_out, int out_size, void* d_ws, size_t ws_size,
                              hipStream_t stream)
{
    const float* features = (const float*)d_in[0];
    const int*   labels   = (const int*)d_in[1];
    const float* W1 = (const float*)d_in[2];
    const float* b1 = (const float*)d_in[3];
    const float* W2 = (const float*)d_in[4];
    const float* b2 = (const float*)d_in[5];
    const float* W3 = (const float*)d_in[6];
    const float* b3 = (const float*)d_in[7];

    float* scores = (float*)d_ws;          // 65536 floats = 256 KiB scratch
    float* out    = (float*)d_out;

    const int nrows = NB * NSEQ;           // 65536
    scores_kernel<<<nrows / ROWS, NTHREADS, 0, stream>>>(
        features, W1, b1, W2, b2, W3, b3, scores);
    lambda_kernel<<<NB, NSEQ, 0, stream>>>(scores, labels, out);
}

// Round 2
// 173.744 us; speedup vs baseline: 1.2925x; 1.2925x over previous
//
#include <hip/hip_runtime.h>
#include <hip/hip_bf16.h>

#define DIN 136
#define HH  128
#define ROWS 32       // rows per block in scores kernel
#define NTHREADS 256
#define NSEQ 256      // N
#define NB   256      // B

// ---------------------------------------------------------------------------
// Kernel 1: scores = MLP(features).  One block = 32 rows (b,n) flattened.
// Thread layout: t = rg*32 + hq;  rg in [0,8) owns rows rg*4..rg*4+3,
// hq in [0,32) owns output columns hq*4..hq*4+3.
// LDS: single buffer, features tile aliased with hidden tile (barrier-fenced).
// 17.4 KiB LDS -> 8 blocks/CU by grid (2048 blocks / 256 CUs).
// ---------------------------------------------------------------------------
__global__ __launch_bounds__(NTHREADS)
void scores_kernel(const float* __restrict__ features,
                   const float* __restrict__ W1, const float* __restrict__ b1,
                   const float* __restrict__ W2, const float* __restrict__ b2,
                   const float* __restrict__ W3, const float* __restrict__ b3,
                   float* __restrict__ scores)
{
    __shared__ float smem[ROWS * DIN];          // 17408 B, dual-use
    float (*fbuf)[DIN] = (float (*)[DIN])smem;  // [32][136]
    float (*hbuf)[HH]  = (float (*)[HH])smem;   // [32][128] aliased

    const int t   = threadIdx.x;
    const int hq  = t & 31;   // column quad
    const int rg  = t >> 5;   // row group (4 rows each)
    const long row0 = (long)blockIdx.x * ROWS;

    // ---- stage features tile (contiguous 32*136 = 4352 floats = 1088 f4) ----
    {
        const float4* fsrc = (const float4*)(features + row0 * DIN);
        for (int i = t; i < ROWS * DIN / 4; i += NTHREADS)
            ((float4*)smem)[i] = fsrc[i];
    }
    __syncthreads();

    float acc[4][4];

    // ---- layer 1: h1 = relu(f @ W1 + b1) ----
    {
        const float4 bv = *(const float4*)&b1[hq * 4];
#pragma unroll
        for (int rr = 0; rr < 4; ++rr) {
            acc[rr][0] = bv.x; acc[rr][1] = bv.y;
            acc[rr][2] = bv.z; acc[rr][3] = bv.w;
        }
        for (int d4 = 0; d4 < DIN / 4; ++d4) {
            const float4 w0 = *(const float4*)&W1[(d4 * 4 + 0) * HH + hq * 4];
            const float4 w1 = *(const float4*)&W1[(d4 * 4 + 1) * HH + hq * 4];
            const float4 w2 = *(const float4*)&W1[(d4 * 4 + 2) * HH + hq * 4];
            const float4 w3 = *(const float4*)&W1[(d4 * 4 + 3) * HH + hq * 4];
#pragma unroll
            for (int rr = 0; rr < 4; ++rr) {
                const float4 f = *(const float4*)&fbuf[rg * 4 + rr][d4 * 4];
                acc[rr][0] += f.x * w0.x + f.y * w1.x + f.z * w2.x + f.w * w3.x;
                acc[rr][1] += f.x * w0.y + f.y * w1.y + f.z * w2.y + f.w * w3.y;
                acc[rr][2] += f.x * w0.z + f.y * w1.z + f.z * w2.z + f.w * w3.z;
                acc[rr][3] += f.x * w0.w + f.y * w1.w + f.z * w2.w + f.w * w3.w;
            }
        }
    }
    __syncthreads();   // all layer-1 reads of fbuf done before overwrite
#pragma unroll
    for (int rr = 0; rr < 4; ++rr) {
        float4 v;
        v.x = fmaxf(acc[rr][0], 0.f); v.y = fmaxf(acc[rr][1], 0.f);
        v.z = fmaxf(acc[rr][2], 0.f); v.w = fmaxf(acc[rr][3], 0.f);
        *(float4*)&hbuf[rg * 4 + rr][hq * 4] = v;
    }
    __syncthreads();

    // ---- layer 2: h2 = relu(h1 @ W2 + b2) ----
    {
        const float4 bv = *(const float4*)&b2[hq * 4];
#pragma unroll
        for (int rr = 0; rr < 4; ++rr) {
            acc[rr][0] = bv.x; acc[rr][1] = bv.y;
            acc[rr][2] = bv.z; acc[rr][3] = bv.w;
        }
        for (int d4 = 0; d4 < HH / 4; ++d4) {
            const float4 w0 = *(const float4*)&W2[(d4 * 4 + 0) * HH + hq * 4];
            const float4 w1 = *(const float4*)&W2[(d4 * 4 + 1) * HH + hq * 4];
            const float4 w2 = *(const float4*)&W2[(d4 * 4 + 2) * HH + hq * 4];
            const float4 w3 = *(const float4*)&W2[(d4 * 4 + 3) * HH + hq * 4];
#pragma unroll
            for (int rr = 0; rr < 4; ++rr) {
                const float4 f = *(const float4*)&hbuf[rg * 4 + rr][d4 * 4];
                acc[rr][0] += f.x * w0.x + f.y * w1.x + f.z * w2.x + f.w * w3.x;
                acc[rr][1] += f.x * w0.y + f.y * w1.y + f.z * w2.y + f.w * w3.y;
                acc[rr][2] += f.x * w0.z + f.y * w1.z + f.z * w2.z + f.w * w3.z;
                acc[rr][3] += f.x * w0.w + f.y * w1.w + f.z * w2.w + f.w * w3.w;
            }
        }
    }

    // ---- layer 3: score = relu(h2) @ W3 + b3, reduce across 32 hq lanes ----
    {
        const float4 w = *(const float4*)&W3[hq * 4];
        const float bias = b3[0];
#pragma unroll
        for (int rr = 0; rr < 4; ++rr) {
            float p = fmaxf(acc[rr][0], 0.f) * w.x + fmaxf(acc[rr][1], 0.f) * w.y +
                      fmaxf(acc[rr][2], 0.f) * w.z + fmaxf(acc[rr][3], 0.f) * w.w;
            p += __shfl_xor(p, 16, 64);
            p += __shfl_xor(p, 8, 64);
            p += __shfl_xor(p, 4, 64);
            p += __shfl_xor(p, 2, 64);
            p += __shfl_xor(p, 1, 64);
            if (hq == 0)
                scores[row0 + rg * 4 + rr] = p + bias;
        }
    }
}

// ---------------------------------------------------------------------------
// Kernel 2: pairwise LambdaRank reduction. One block per query b, 1024 threads:
// i = t&255 owns row i, jg = t>>8 covers j in [jg*64, jg*64+64). Branchless
// body (li==lj => dndcg==0), LDS partial-sum reduce over the 4 j-groups.
// ---------------------------------------------------------------------------
#define JT 4
__global__ __launch_bounds__(NSEQ * JT)
void lambda_kernel(const float* __restrict__ scores,
                   const int* __restrict__ labels,
                   float* __restrict__ out)
{
    __shared__ float s_sc[NSEQ];
    __shared__ float s_gain[NSEQ];
    __shared__ int   s_lab[NSEQ];
    __shared__ float s_part[JT][NSEQ];

    const int b  = blockIdx.x;
    const int t  = threadIdx.x;
    const int i  = t & (NSEQ - 1);
    const int jg = t >> 8;

    if (jg == 0) {
        const float sv = scores[b * NSEQ + i];
        const int   lv = labels[b * NSEQ + i];
        s_sc[i]   = sv;
        s_lab[i]  = lv;
        s_gain[i] = exp2f((float)lv);
    }
    __syncthreads();

    const float si = s_sc[i];
    const int   li = s_lab[i];
    const float gi = s_gain[i];

    float accum = 0.f;
#pragma unroll 4
    for (int jj = 0; jj < NSEQ / JT; ++jj) {
        const int j = jg * (NSEQ / JT) + jj;
        const int   lj = s_lab[j];
        const float sj = s_sc[j];
        const float gj = s_gain[j];
        const float mx = fmaxf(si, sj);
        const float dn = fabsf(gi - gj) *
                         __builtin_amdgcn_rcpf(1.f + log2f(1.f + mx));
        // sigmoid(si-sj) via native exp2
        const float sig = __builtin_amdgcn_rcpf(
            1.f + exp2f((sj - si) * 1.44269504088896f));
        const float w = (li > lj) ? sig : (sig - 1.f);   // li==lj -> dn==0
        accum += 0.5f * dn * w;
    }
    s_part[jg][i] = accum;
    __syncthreads();

    if (jg == 0)
        out[b * NSEQ + i] = s_part[0][i] + s_part[1][i] +
                            s_part[2][i] + s_part[3][i];
}

// ---------------------------------------------------------------------------
extern "C" void kernel_launch(void* const* d_in, const int* in_sizes, int n_in,
                              void* d_out, int out_size, void* d_ws, size_t ws_size,
                              hipStream_t stream)
{
    const float* features = (const float*)d_in[0];
    const int*   labels   = (const int*)d_in[1];
    const float* W1 = (const float*)d_in[2];
    const float* b1 = (const float*)d_in[3];
    const float* W2 = (const float*)d_in[4];
    const float* b2 = (const float*)d_in[5];
    const float* W3 = (const float*)d_in[6];
    const float* b3 = (const float*)d_in[7];

    float* scores = (float*)d_ws;          // 65536 floats = 256 KiB scratch
    float* out    = (float*)d_out;

    const int nrows = NB * NSEQ;           // 65536
    scores_kernel<<<nrows / ROWS, NTHREADS, 0, stream>>>(
        features, W1, b1, W2, b2, W3, b3, scores);
    lambda_kernel<<<NB, NSEQ * JT, 0, stream>>>(scores, labels, out);
}

// Round 3
// 126.837 us; speedup vs baseline: 1.7705x; 1.3698x over previous
//
#include <hip/hip_runtime.h>
#include <hip/hip_bf16.h>

#define DIN  136
#define HH   128
#define NSEQ 256
#define NB   256
#define BROWS 128          // rows per scores block
#define SKS  136           // LDS row stride in elements (272B -> 2-way bank alias, free)

typedef __attribute__((ext_vector_type(4))) float f32x4;
typedef __attribute__((ext_vector_type(2))) float f32x2;
typedef __attribute__((ext_vector_type(8))) short bf16x8;

static __device__ __forceinline__ unsigned short f2bf(float f) {
    unsigned int u = __float_as_uint(f);
    u += 0x7fffu + ((u >> 16) & 1u);          // round-to-nearest-even
    return (unsigned short)(u >> 16);
}

// ---------------------------------------------------------------------------
// Kernel 1: bf16-MFMA MLP. Block = 128 rows, 256 threads (4 waves).
// Wave w owns row-tiles {2w,2w+1} x all 8 col-tiles (16x16 each).
// Also emits per-row pack {score, gain, discount, label} and zeroes d_out.
// ---------------------------------------------------------------------------
__global__ __launch_bounds__(256)
void scores_mfma_kernel(const float* __restrict__ features,
                        const int*   __restrict__ labels,
                        const float* __restrict__ W1, const float* __restrict__ b1,
                        const float* __restrict__ W2, const float* __restrict__ b2,
                        const float* __restrict__ W3, const float* __restrict__ b3,
                        float4* __restrict__ pack,
                        float* __restrict__ out_zero)
{
    __shared__ short a_lds[BROWS * SKS];   // 34816 B: features tile, later h1
    __shared__ short w_lds[HH * SKS];      // 34816 B: W1^T, later W2^T

    const int t    = threadIdx.x;
    const int lane = t & 63;
    const int wv   = t >> 6;
    const int l15  = lane & 15;
    const int l4   = lane >> 4;
    const long row0 = (long)blockIdx.x * BROWS;

    // ---- stage features (linear, fp32->bf16) ----
    {
        const f32x2* src = (const f32x2*)(features + row0 * DIN);
        for (int i = t; i < BROWS * DIN / 2; i += 256) {
            f32x2 v = src[i];
            unsigned int p = (unsigned int)f2bf(v.x) | ((unsigned int)f2bf(v.y) << 16);
            ((unsigned int*)a_lds)[i] = p;
        }
    }
    // ---- stage W1 transposed: w_lds[n][k] = bf16(W1[k][n]) ----
    {
        const f32x2* src = (const f32x2*)W1;
        for (int i = t; i < DIN * HH / 2; i += 256) {
            f32x2 v = src[i];
            const int e = i * 2, k = e >> 7, n = e & 127;
            w_lds[n * SKS + k]       = (short)f2bf(v.x);
            w_lds[(n + 1) * SKS + k] = (short)f2bf(v.y);
        }
    }
    __syncthreads();

    // ---- layer 1: h1 = relu(A @ W1 + b1), K = 136 = 4*32 + 8 ----
    f32x4 acc[2][8];
#pragma unroll
    for (int tn = 0; tn < 8; ++tn) {
        const float bv = b1[tn * 16 + l15];
#pragma unroll
        for (int tm = 0; tm < 2; ++tm) acc[tm][tn] = (f32x4){bv, bv, bv, bv};
    }
    for (int kc = 0; kc < 5; ++kc) {
        bf16x8 afr[2], bfr[8];
        if (kc < 4) {
            const int kb = kc * 32 + l4 * 8;
#pragma unroll
            for (int tm = 0; tm < 2; ++tm)
                afr[tm] = *(const bf16x8*)&a_lds[((wv * 2 + tm) * 16 + l15) * SKS + kb];
#pragma unroll
            for (int tn = 0; tn < 8; ++tn)
                bfr[tn] = *(const bf16x8*)&w_lds[(tn * 16 + l15) * SKS + kb];
        } else {
            if (l4 == 0) {   // tail k = 128..135: only k-group 0 is real
#pragma unroll
                for (int tm = 0; tm < 2; ++tm)
                    afr[tm] = *(const bf16x8*)&a_lds[((wv * 2 + tm) * 16 + l15) * SKS + 128];
#pragma unroll
                for (int tn = 0; tn < 8; ++tn)
                    bfr[tn] = *(const bf16x8*)&w_lds[(tn * 16 + l15) * SKS + 128];
            } else {
#pragma unroll
                for (int tm = 0; tm < 2; ++tm) afr[tm] = (bf16x8){0,0,0,0,0,0,0,0};
#pragma unroll
                for (int tn = 0; tn < 8; ++tn) bfr[tn] = (bf16x8){0,0,0,0,0,0,0,0};
            }
        }
#pragma unroll
        for (int tm = 0; tm < 2; ++tm)
#pragma unroll
            for (int tn = 0; tn < 8; ++tn)
                acc[tm][tn] = __builtin_amdgcn_mfma_f32_16x16x32_bf16(
                    afr[tm], bfr[tn], acc[tm][tn], 0, 0, 0);
    }
    __syncthreads();   // all reads of a_lds/w_lds complete

    // ---- store relu(h1) as bf16 into a_lds; stage W2^T into w_lds ----
    // C/D layout: row=(l>>4)*4+j, col=l&15  [m89/m91 verified]
#pragma unroll
    for (int tm = 0; tm < 2; ++tm) {
        const int rbase = (wv * 2 + tm) * 16 + l4 * 4;
#pragma unroll
        for (int tn = 0; tn < 8; ++tn) {
            const int col = tn * 16 + l15;
#pragma unroll
            for (int j = 0; j < 4; ++j)
                a_lds[(rbase + j) * SKS + col] = (short)f2bf(fmaxf(acc[tm][tn][j], 0.f));
        }
    }
    {
        const f32x2* src = (const f32x2*)W2;
        for (int i = t; i < HH * HH / 2; i += 256) {
            f32x2 v = src[i];
            const int e = i * 2, k = e >> 7, n = e & 127;
            w_lds[n * SKS + k]       = (short)f2bf(v.x);
            w_lds[(n + 1) * SKS + k] = (short)f2bf(v.y);
        }
    }
    __syncthreads();

    // ---- layer 2: h2 = relu(h1 @ W2 + b2), K = 128 ----
    f32x4 acc2[2][8];
#pragma unroll
    for (int tn = 0; tn < 8; ++tn) {
        const float bv = b2[tn * 16 + l15];
#pragma unroll
        for (int tm = 0; tm < 2; ++tm) acc2[tm][tn] = (f32x4){bv, bv, bv, bv};
    }
    for (int kc = 0; kc < 4; ++kc) {
        const int kb = kc * 32 + l4 * 8;
        bf16x8 afr[2], bfr[8];
#pragma unroll
        for (int tm = 0; tm < 2; ++tm)
            afr[tm] = *(const bf16x8*)&a_lds[((wv * 2 + tm) * 16 + l15) * SKS + kb];
#pragma unroll
        for (int tn = 0; tn < 8; ++tn)
            bfr[tn] = *(const bf16x8*)&w_lds[(tn * 16 + l15) * SKS + kb];
#pragma unroll
        for (int tm = 0; tm < 2; ++tm)
#pragma unroll
            for (int tn = 0; tn < 8; ++tn)
                acc2[tm][tn] = __builtin_amdgcn_mfma_f32_16x16x32_bf16(
                    afr[tm], bfr[tn], acc2[tm][tn], 0, 0, 0);
    }

    // ---- layer 3 + pack: score = relu(h2) @ W3 + b3 ----
    {
        float w3v[8];
#pragma unroll
        for (int tn = 0; tn < 8; ++tn) w3v[tn] = W3[tn * 16 + l15];
        const float b3v = b3[0];
#pragma unroll
        for (int tm = 0; tm < 2; ++tm) {
#pragma unroll
            for (int j = 0; j < 4; ++j) {
                float p = 0.f;
#pragma unroll
                for (int tn = 0; tn < 8; ++tn)
                    p += fmaxf(acc2[tm][tn][j], 0.f) * w3v[tn];
                p += __shfl_xor(p, 1, 64);
                p += __shfl_xor(p, 2, 64);
                p += __shfl_xor(p, 4, 64);
                p += __shfl_xor(p, 8, 64);
                if (l15 == 0) {
                    const int row = (wv * 2 + tm) * 16 + l4 * 4 + j;
                    const long gr = row0 + row;
                    const float s = p + b3v;
                    const int lab = labels[gr];
                    const float g = exp2f((float)lab);
                    const float disc = 1.f / (1.f + log2f(1.f + s));
                    pack[gr] = make_float4(s, g, disc, __int_as_float(lab));
                    out_zero[gr] = 0.f;
                }
            }
        }
    }
}

// ---------------------------------------------------------------------------
// Kernel 2: pairwise lambdas. Block = (query b, j-quarter jq); thread t = i.
// Per pair: 2 trans (exp2, rcp) + ~11 VALU + 1 broadcast ds_read_b128.
// Partials accumulated with atomicAdd into out (zeroed by kernel 1).
// ---------------------------------------------------------------------------
__global__ __launch_bounds__(256)
void lambda_pair_kernel(const float4* __restrict__ pack,
                        float* __restrict__ out)
{
    __shared__ float4 sp[NSEQ];
    const int t  = threadIdx.x;
    const int b  = blockIdx.x >> 2;
    const int jq = blockIdx.x & 3;

    const float4 me = pack[b * NSEQ + t];
    sp[t] = me;
    __syncthreads();

    const float si = me.x, gi = me.y, di = me.z;
    const int   li = __float_as_int(me.w);

    float accum = 0.f;
    const int j0 = jq * 64;
#pragma unroll 8
    for (int jj = 0; jj < 64; ++jj) {
        const float4 o = sp[j0 + jj];
        const float sj = o.x, gj = o.y, dj = o.z;
        const int   lj = __float_as_int(o.w);
        const float dmax = (si > sj) ? di : dj;        // discount of max score
        const float dn   = fabsf(gi - gj) * dmax;      // 0 when li==lj
        const float e    = exp2f((sj - si) * 1.44269504f);
        const float sig  = __builtin_amdgcn_rcpf(1.f + e);
        const float w    = (li > lj) ? sig : (sig - 1.f);
        accum += 0.5f * dn * w;
    }
    atomicAdd(&out[b * NSEQ + t], accum);
}

// ---------------------------------------------------------------------------
extern "C" void kernel_launch(void* const* d_in, const int* in_sizes, int n_in,
                              void* d_out, int out_size, void* d_ws, size_t ws_size,
                              hipStream_t stream)
{
    const float* features = (const float*)d_in[0];
    const int*   labels   = (const int*)d_in[1];
    const float* W1 = (const float*)d_in[2];
    const float* b1 = (const float*)d_in[3];
    const float* W2 = (const float*)d_in[4];
    const float* b2 = (const float*)d_in[5];
    const float* W3 = (const float*)d_in[6];
    const float* b3 = (const float*)d_in[7];

    float4* pack = (float4*)d_ws;          // 65536 * 16B = 1 MiB scratch
    float*  out  = (float*)d_out;

    scores_mfma_kernel<<<NB * NSEQ / BROWS, 256, 0, stream>>>(
        features, labels, W1, b1, W2, b2, W3, b3, pack, out);
    lambda_pair_kernel<<<NB * 4, 256, 0, stream>>>(pack, out);
}

// Round 4
// 124.434 us; speedup vs baseline: 1.8047x; 1.0193x over previous
//
#include <hip/hip_runtime.h>
#include <hip/hip_bf16.h>

#define DIN  136
#define HH   128
#define NSEQ 256
#define NB   256
#define BROWS 64
#define K1P  168          // padded K / LDS row stride (168*2B stride -> benign banks)
#define JB   8            // j-blocks per query in lambda kernel

typedef __attribute__((ext_vector_type(4))) float f32x4;
typedef __attribute__((ext_vector_type(2))) float f32x2;
typedef __attribute__((ext_vector_type(8))) short bf16x8;

static __device__ __forceinline__ unsigned short f2bf(float f) {
    unsigned int u = __float_as_uint(f);
    u += 0x7fffu + ((u >> 16) & 1u);          // round-to-nearest-even
    return (unsigned short)(u >> 16);
}

// ---------------------------------------------------------------------------
// Prep: bf16 W1^T [HH][K1P] (zero-padded K>=136) and W2^T [HH][HH], done once
// per launch instead of once per scores block.
// ---------------------------------------------------------------------------
__global__ __launch_bounds__(256)
void prep_kernel(const float* __restrict__ W1, const float* __restrict__ W2,
                 short* __restrict__ w1t, short* __restrict__ w2t)
{
    const int nt = gridDim.x * 256;
    const int idx = blockIdx.x * 256 + threadIdx.x;
    for (int e = idx; e < HH * K1P; e += nt) {
        const int n = e / K1P, k = e - n * K1P;
        w1t[e] = (k < DIN) ? (short)f2bf(W1[k * HH + n]) : (short)0;
    }
    for (int e = idx; e < HH * HH; e += nt) {
        const int n = e >> 7, k = e & 127;
        w2t[e] = (short)f2bf(W2[k * HH + n]);
    }
}

// ---------------------------------------------------------------------------
// Scores MLP via bf16 MFMA. Block = 64 rows, 4 waves; wave w owns row-tile w.
// B-fragments come straight from global bf16 W^T (L1/L2-hot, same for all
// waves). LDS only holds the features/h1 tile (21.5 KiB).
// Emits pack {s*log2e, 0.5*gain, discount, 0} and zeroes d_out.
// ---------------------------------------------------------------------------
__global__ __launch_bounds__(256)
void scores_mfma_kernel(const float* __restrict__ features,
                        const int*   __restrict__ labels,
                        const short* __restrict__ w1t,
                        const short* __restrict__ w2t,
                        const float* __restrict__ b1, const float* __restrict__ b2,
                        const float* __restrict__ W3, const float* __restrict__ b3,
                        float4* __restrict__ pack,
                        float* __restrict__ out_zero)
{
    __shared__ short a_lds[BROWS * K1P];      // 21504 B

    const int t    = threadIdx.x;
    const int lane = t & 63;
    const int wv   = t >> 6;
    const int l15  = lane & 15;
    const int l4   = lane >> 4;
    const long row0 = (long)blockIdx.x * BROWS;

    // ---- stage features (fp32 -> bf16, pairs stay within a row: DIN even) ----
    {
        const f32x2* src = (const f32x2*)(features + row0 * DIN);
        for (int i = t; i < BROWS * DIN / 2; i += 256) {
            f32x2 v = src[i];
            const int e = i * 2;
            const int r = e / DIN, k = e - r * DIN;
            *(unsigned int*)&a_lds[r * K1P + k] =
                (unsigned int)f2bf(v.x) | ((unsigned int)f2bf(v.y) << 16);
        }
        // zero-pad k in [136,168): 16 u32 per row
        for (int i = t; i < BROWS * 16; i += 256) {
            const int r = i >> 4, k = DIN + (i & 15) * 2;
            *(unsigned int*)&a_lds[r * K1P + k] = 0u;
        }
    }
    __syncthreads();

    const int arow = (wv * 16 + l15) * K1P;

    // ---- layer 1: h1 = relu(A @ W1 + b1), K = 160 (zero-padded) ----
    f32x4 acc[8];
#pragma unroll
    for (int tn = 0; tn < 8; ++tn) {
        const float bv = b1[tn * 16 + l15];
        acc[tn] = (f32x4){bv, bv, bv, bv};
    }
    for (int kc = 0; kc < 5; ++kc) {
        const int kb = kc * 32 + l4 * 8;
        const bf16x8 afr = *(const bf16x8*)&a_lds[arow + kb];
        bf16x8 bfr[8];
#pragma unroll
        for (int tn = 0; tn < 8; ++tn)
            bfr[tn] = *(const bf16x8*)&w1t[(tn * 16 + l15) * K1P + kb];
#pragma unroll
        for (int tn = 0; tn < 8; ++tn)
            acc[tn] = __builtin_amdgcn_mfma_f32_16x16x32_bf16(afr, bfr[tn], acc[tn], 0, 0, 0);
    }
    __syncthreads();

    // ---- store relu(h1) bf16 back to a_lds (wave-private rows) ----
    // C/D layout: row = l4*4+j (within tile), col = l15  [m89/m91]
#pragma unroll
    for (int tn = 0; tn < 8; ++tn) {
        const int col = tn * 16 + l15;
#pragma unroll
        for (int j = 0; j < 4; ++j)
            a_lds[(wv * 16 + l4 * 4 + j) * K1P + col] =
                (short)f2bf(fmaxf(acc[tn][j], 0.f));
    }
    __syncthreads();

    // ---- layer 2: h2 = relu(h1 @ W2 + b2), K = 128 ----
    f32x4 acc2[8];
#pragma unroll
    for (int tn = 0; tn < 8; ++tn) {
        const float bv = b2[tn * 16 + l15];
        acc2[tn] = (f32x4){bv, bv, bv, bv};
    }
    for (int kc = 0; kc < 4; ++kc) {
        const int kb = kc * 32 + l4 * 8;
        const bf16x8 afr = *(const bf16x8*)&a_lds[arow + kb];
        bf16x8 bfr[8];
#pragma unroll
        for (int tn = 0; tn < 8; ++tn)
            bfr[tn] = *(const bf16x8*)&w2t[(tn * 16 + l15) * HH + kb];
#pragma unroll
        for (int tn = 0; tn < 8; ++tn)
            acc2[tn] = __builtin_amdgcn_mfma_f32_16x16x32_bf16(afr, bfr[tn], acc2[tn], 0, 0, 0);
    }

    // ---- layer 3 + pack ----
    {
        float w3v[8];
#pragma unroll
        for (int tn = 0; tn < 8; ++tn) w3v[tn] = W3[tn * 16 + l15];
        const float b3v = b3[0];
#pragma unroll
        for (int j = 0; j < 4; ++j) {
            float p = 0.f;
#pragma unroll
            for (int tn = 0; tn < 8; ++tn)
                p += fmaxf(acc2[tn][j], 0.f) * w3v[tn];
            p += __shfl_xor(p, 1, 64);
            p += __shfl_xor(p, 2, 64);
            p += __shfl_xor(p, 4, 64);
            p += __shfl_xor(p, 8, 64);
            if (l15 == 0) {
                const int row = wv * 16 + l4 * 4 + j;
                const long gr = row0 + row;
                const float s = p + b3v;
                const int lab = labels[gr];
                const float g = 0.5f * exp2f((float)lab);        // 0.5 folded
                const float disc = 1.f / (1.f + log2f(1.f + s));
                pack[gr] = make_float4(s * 1.44269504088896f,    // log2e folded
                                       g, disc, 0.f);
                out_zero[gr] = 0.f;
            }
        }
    }
}

// ---------------------------------------------------------------------------
// Pairwise lambdas. Block = (query b, j-eighth); thread t = i, 32 j per block.
// gain is strictly monotone in label, so the label compare is sign(gj-gi).
// 9 VALU + 2 trans + 1 broadcast ds_read_b128 per pair.
// ---------------------------------------------------------------------------
__global__ __launch_bounds__(256)
void lambda_pair_kernel(const float4* __restrict__ pack,
                        float* __restrict__ out)
{
    __shared__ float4 sp[NSEQ];
    const int t  = threadIdx.x;
    const int b  = blockIdx.x >> 3;
    const int jo = (blockIdx.x & 7) * (NSEQ / JB);

    const float4 me = pack[b * NSEQ + t];
    sp[t] = me;
    __syncthreads();

    const float sci = me.x, gi = me.y, di = me.z;
    float accum = 0.f;
#pragma unroll 8
    for (int jj = 0; jj < NSEQ / JB; ++jj) {
        const float4 o = sp[jo + jj];
        const float dg = o.y - gi;                         // (gj-gi)/2
        const float e  = exp2f(o.x - sci);                 // exp(sj-si)
        const float r  = __builtin_amdgcn_rcpf(1.f + e);   // sigmoid(si-sj)
        const float dmax = (sci > o.x) ? di : o.z;         // discount of max
        const float dn = fabsf(dg) * dmax;                 // 0 when li==lj
        const float w  = (dg < 0.f) ? r : (r - 1.f);
        accum += dn * w;
    }
    atomicAdd(&out[b * NSEQ + t], accum);
}

// ---------------------------------------------------------------------------
extern "C" void kernel_launch(void* const* d_in, const int* in_sizes, int n_in,
                              void* d_out, int out_size, void* d_ws, size_t ws_size,
                              hipStream_t stream)
{
    const float* features = (const float*)d_in[0];
    const int*   labels   = (const int*)d_in[1];
    const float* W1 = (const float*)d_in[2];
    const float* b1 = (const float*)d_in[3];
    const float* W2 = (const float*)d_in[4];
    const float* b2 = (const float*)d_in[5];
    const float* W3 = (const float*)d_in[6];
    const float* b3 = (const float*)d_in[7];

    float4* pack = (float4*)d_ws;                                  // 1 MiB
    short*  w1t  = (short*)((char*)d_ws + (size_t)NB * NSEQ * 16); // 21504 el
    short*  w2t  = w1t + HH * K1P;                                 // 16384 el
    float*  out  = (float*)d_out;

    prep_kernel<<<64, 256, 0, stream>>>(W1, W2, w1t, w2t);
    scores_mfma_kernel<<<NB * NSEQ / BROWS, 256, 0, stream>>>(
        features, labels, w1t, w2t, b1, b2, W3, b3, pack, out);
    lambda_pair_kernel<<<NB * JB, 256, 0, stream>>>(pack, out);
}

// Round 5
// 121.806 us; speedup vs baseline: 1.8437x; 1.0216x over previous
//
#include <hip/hip_runtime.h>
#include <hip/hip_bf16.h>

#define DIN  136
#define HH   128
#define NSEQ 256
#define NB   256
#define K1P  168          // padded K / LDS row stride in elements

typedef __attribute__((ext_vector_type(4))) float f32x4;
typedef __attribute__((ext_vector_type(2))) float f32x2;
typedef __attribute__((ext_vector_type(8))) short bf16x8;

static __device__ __forceinline__ unsigned short f2bf(float f) {
    unsigned int u = __float_as_uint(f);
    u += 0x7fffu + ((u >> 16) & 1u);          // round-to-nearest-even
    return (unsigned short)(u >> 16);
}

// ---------------------------------------------------------------------------
// Prep: bf16 W1^T [HH][K1P] (zero-padded K>=136) and W2^T [HH][HH], once.
// ---------------------------------------------------------------------------
__global__ __launch_bounds__(256)
void prep_kernel(const float* __restrict__ W1, const float* __restrict__ W2,
                 short* __restrict__ w1t, short* __restrict__ w2t)
{
    const int nt = gridDim.x * 256;
    const int idx = blockIdx.x * 256 + threadIdx.x;
    for (int e = idx; e < HH * K1P; e += nt) {
        const int n = e / K1P, k = e - n * K1P;
        w1t[e] = (k < DIN) ? (short)f2bf(W1[k * HH + n]) : (short)0;
    }
    for (int e = idx; e < HH * HH; e += nt) {
        const int n = e >> 7, k = e & 127;
        w2t[e] = (short)f2bf(W2[k * HH + n]);
    }
}

// ---------------------------------------------------------------------------
// Fused kernel: one block = one query (256 rows), 1024 threads = 16 waves.
// Wave w owns row-tile w (16 rows) through both MFMA layers; relu(h1) is
// written back in place to the wave's own rows (same-wave DS ordering ->
// no barriers between layers). After layer 3, per-row pack {s*log2e,
// 0.5*gain, discount} goes to LDS; one barrier; then the block computes its
// query's 256x256 pairwise lambdas and writes out directly (no atomics).
// ---------------------------------------------------------------------------
__global__ __launch_bounds__(1024, 4)
void fused_kernel(const float* __restrict__ features,
                  const int*   __restrict__ labels,
                  const short* __restrict__ w1t,
                  const short* __restrict__ w2t,
                  const float* __restrict__ b1, const float* __restrict__ b2,
                  const float* __restrict__ W3, const float* __restrict__ b3,
                  float* __restrict__ out)
{
    __shared__ short  a_lds[NSEQ * K1P];   // 86016 B: features tile, then h1
    __shared__ float4 sp[NSEQ];            // 4 KB: per-row pack
    __shared__ float  s_part[4][NSEQ];     // 4 KB: lambda partials

    const int t    = threadIdx.x;
    const int lane = t & 63;
    const int wv   = t >> 6;      // 0..15: row-tile owner
    const int l15  = lane & 15;
    const int l4   = lane >> 4;
    const long row0 = (long)blockIdx.x * NSEQ;   // query index = blockIdx.x

    // ---- stage features (fp32 -> bf16; DIN even so pairs stay in-row) ----
    {
        const f32x2* src = (const f32x2*)(features + row0 * DIN);
        for (int i = t; i < NSEQ * DIN / 2; i += 1024) {
            f32x2 v = src[i];
            const int e = i * 2;
            const int r = e / DIN, k = e - r * DIN;
            *(unsigned int*)&a_lds[r * K1P + k] =
                (unsigned int)f2bf(v.x) | ((unsigned int)f2bf(v.y) << 16);
        }
        for (int i = t; i < NSEQ * 16; i += 1024) {     // zero-pad k 136..167
            const int r = i >> 4, k = DIN + (i & 15) * 2;
            *(unsigned int*)&a_lds[r * K1P + k] = 0u;
        }
    }
    __syncthreads();

    const int arow = (wv * 16 + l15) * K1P;

    // ---- layer 1: h1 = relu(A @ W1 + b1), K = 160 (zero-padded) ----
    f32x4 acc[8];
#pragma unroll
    for (int tn = 0; tn < 8; ++tn) {
        const float bv = b1[tn * 16 + l15];
        acc[tn] = (f32x4){bv, bv, bv, bv};
    }
    for (int kc = 0; kc < 5; ++kc) {
        const int kb = kc * 32 + l4 * 8;
        const bf16x8 afr = *(const bf16x8*)&a_lds[arow + kb];
        bf16x8 bfr[8];
#pragma unroll
        for (int tn = 0; tn < 8; ++tn)
            bfr[tn] = *(const bf16x8*)&w1t[(tn * 16 + l15) * K1P + kb];
#pragma unroll
        for (int tn = 0; tn < 8; ++tn)
            acc[tn] = __builtin_amdgcn_mfma_f32_16x16x32_bf16(afr, bfr[tn], acc[tn], 0, 0, 0);
    }

    // ---- relu(h1) -> bf16, in place into the wave's OWN rows (no barrier;
    //      same-wave DS ops complete in order, and only wave wv ever touches
    //      rows [wv*16, wv*16+16)).  C/D layout: row=l4*4+j, col=l15. ----
#pragma unroll
    for (int tn = 0; tn < 8; ++tn) {
        const int col = tn * 16 + l15;
#pragma unroll
        for (int j = 0; j < 4; ++j)
            a_lds[(wv * 16 + l4 * 4 + j) * K1P + col] =
                (short)f2bf(fmaxf(acc[tn][j], 0.f));
    }

    // ---- layer 2: h2 = relu(h1 @ W2 + b2), K = 128 ----
    f32x4 acc2[8];
#pragma unroll
    for (int tn = 0; tn < 8; ++tn) {
        const float bv = b2[tn * 16 + l15];
        acc2[tn] = (f32x4){bv, bv, bv, bv};
    }
    for (int kc = 0; kc < 4; ++kc) {
        const int kb = kc * 32 + l4 * 8;
        const bf16x8 afr = *(const bf16x8*)&a_lds[arow + kb];
        bf16x8 bfr[8];
#pragma unroll
        for (int tn = 0; tn < 8; ++tn)
            bfr[tn] = *(const bf16x8*)&w2t[(tn * 16 + l15) * HH + kb];
#pragma unroll
        for (int tn = 0; tn < 8; ++tn)
            acc2[tn] = __builtin_amdgcn_mfma_f32_16x16x32_bf16(afr, bfr[tn], acc2[tn], 0, 0, 0);
    }

    // ---- layer 3 + per-row pack {s*log2e, 0.5*gain, disc} into LDS ----
    {
        float w3v[8];
#pragma unroll
        for (int tn = 0; tn < 8; ++tn) w3v[tn] = W3[tn * 16 + l15];
        const float b3v = b3[0];
#pragma unroll
        for (int j = 0; j < 4; ++j) {
            float p = 0.f;
#pragma unroll
            for (int tn = 0; tn < 8; ++tn)
                p += fmaxf(acc2[tn][j], 0.f) * w3v[tn];
            p += __shfl_xor(p, 1, 64);
            p += __shfl_xor(p, 2, 64);
            p += __shfl_xor(p, 4, 64);
            p += __shfl_xor(p, 8, 64);
            if (l15 == 0) {
                const int row = wv * 16 + l4 * 4 + j;
                const float s = p + b3v;
                const int lab = labels[row0 + row];
                const float g = 0.5f * exp2f((float)lab);      // 0.5 folded
                const float disc = 1.f / (1.f + log2f(1.f + s));
                sp[row] = make_float4(s * 1.44269504088896f,   // log2e folded
                                      g, disc, 0.f);
            }
        }
    }
    __syncthreads();

    // ---- pairwise lambdas for this query: i = t&255, jg = t>>8 (64 j each).
    //      gain strictly monotone in label -> label compare = sign(gj-gi). ----
    {
        const int i  = t & (NSEQ - 1);
        const int jg = t >> 8;
        const float4 me = sp[i];
        const float sci = me.x, gi = me.y, di = me.z;
        float accum = 0.f;
        const int j0 = jg * 64;
#pragma unroll 8
        for (int jj = 0; jj < 64; ++jj) {
            const float4 o = sp[j0 + jj];
            const float dg = o.y - gi;                         // (gj-gi)/2
            const float e  = exp2f(o.x - sci);                 // exp(sj-si)
            const float r  = __builtin_amdgcn_rcpf(1.f + e);   // sigmoid(si-sj)
            const float dmax = (sci > o.x) ? di : o.z;         // disc of max
            const float dn = fabsf(dg) * dmax;                 // 0 when li==lj
            const float w  = (dg < 0.f) ? r : (r - 1.f);
            accum += dn * w;
        }
        s_part[jg][i] = accum;
    }
    __syncthreads();
    {
        const int i  = t & (NSEQ - 1);
        if ((t >> 8) == 0)
            out[row0 + i] = s_part[0][i] + s_part[1][i] +
                            s_part[2][i] + s_part[3][i];
    }
}

// ---------------------------------------------------------------------------
extern "C" void kernel_launch(void* const* d_in, const int* in_sizes, int n_in,
                              void* d_out, int out_size, void* d_ws, size_t ws_size,
                              hipStream_t stream)
{
    const float* features = (const float*)d_in[0];
    const int*   labels   = (const int*)d_in[1];
    const float* W1 = (const float*)d_in[2];
    const float* b1 = (const float*)d_in[3];
    const float* W2 = (const float*)d_in[4];
    const float* b2 = (const float*)d_in[5];
    const float* W3 = (const float*)d_in[6];
    const float* b3 = (const float*)d_in[7];

    short* w1t = (short*)d_ws;             // 128*168 bf16
    short* w2t = w1t + HH * K1P;           // 128*128 bf16
    float* out = (float*)d_out;

    prep_kernel<<<64, 256, 0, stream>>>(W1, W2, w1t, w2t);
    fused_kernel<<<NB, 1024, 0, stream>>>(
        features, labels, w1t, w2t, b1, b2, W3, b3, out);
}